// Round 13
// baseline (3769.740 us; speedup 1.0000x reference)
//
#include <hip/hip_runtime.h>
#include <cmath>

namespace {
constexpr int kNZ = 300, kNX = 400;
constexpr int kNPML = 32;
constexpr int kNZP = 364, kNXP = 464;        // padded physical grid
constexpr int kNSTEPS = 200, kNSHOTS = 2;
constexpr int kSRC_Z = 34, kREC_Z = 34;      // NPML + 2
constexpr float kDT = 0.001f;
constexpr float kINV_DX = 100.0f;            // 1/DX

// persistent slab decomposition — kR=4 (r11-verified geometry/numerics)
constexpr int kR = 4;                         // rows per slab
constexpr int kNSLAB = 92;                    // 368 rows; 364..367 dead (zero moduli)
constexpr int kNB = kNSLAB - 1;               // 91 boundaries
constexpr int kBlocks = kNSHOTS * kNSLAB;     // 184 blocks, all co-resident
constexpr int kThreads = 512;                 // one column per thread (464 active)
constexpr int kPitch = 468;                   // LDS row pitch (guard cols 0,465)
constexpr int kFStride = kR * kPitch;         // 1872

// ws layout (floats / ints):
//   [0, 8192)    : int flags[shot][b][dir] padded x16  (2*91*2*16 = 5824 used)
//   [8192, ...)  : float halo[buf][shot][b][dir][slot(6)][464]  (double-buffered)
//   loss         : 1 float after halos
constexpr int kFlagStride = 16;
constexpr int kHaloBase = 8192;
constexpr int kHaloCount = 2 * kNSHOTS * kNB * 2 * 6 * kNXP;   // 2,026,752
constexpr int kLossOff = kHaloBase + kHaloCount;
}  // namespace

// Only flags + loss need zeroing: t=0 skips ghost loads entirely.
__global__ void fwi_init_ws(float* __restrict__ ws) {
    const int gtid = blockIdx.x * blockDim.x + threadIdx.x;
    const int gstride = gridDim.x * blockDim.x;
    for (int q = gtid; q < kHaloBase; q += gstride) ws[q] = 0.0f;
    if (gtid == 0) ws[kLossOff] = 0.0f;
}

// Persistent kernel, ONE neighbor sync per timestep (r11 numerics, verified).
// NEW (r13): bulk halo data moves as PLAIN coalesced loads/stores; coherence
// via one acquire/release agent fence per step around relaxed flags:
//   producer: plain stores -> __syncthreads (vmcnt drain to L2) ->
//             fence(release, agent) [L2 writeback] -> relaxed flag store
//   consumer: relaxed flag poll -> barrier -> fence(acquire, agent)
//             [L1/L2 invalidate; hot state is regs/LDS so this is cheap] ->
//             plain ghost loads (fetch fresh from LLC)
__global__ __launch_bounds__(kThreads, 1) void fwi_sim_kernel(
    const float* __restrict__ Vp, const float* __restrict__ Vs,
    const float* __restrict__ Den, const float* __restrict__ Stf,
    const int* __restrict__ Shot_ids, float* __restrict__ ws) {
    __shared__ float L[4 * kFStride];   // 29952 B
    float* Lvx  = L;
    float* Lvz  = L + kFStride;
    float* Lsxx = L + 2 * kFStride;
    float* Lsxz = L + 3 * kFStride;

    const int blk  = blockIdx.x;
    const int s    = blk / kNSLAB;
    const int slab = blk - s * kNSLAB;
    const int r0   = slab * kR;
    const int tid  = threadIdx.x;
    const bool active = tid < kNXP;
    const int lc = tid + 1;

    int*   flags = (int*)ws;
    float* halo  = ws + kHaloBase;
    float* lossp = ws + kLossOff;

    for (int q = tid; q < 4 * kFStride; q += kThreads) L[q] = 0.0f;

    auto modAt = [&](int i, int j, float& dtr_, float& dmp_, float& lam_,
                     float& mu_, float& l2m_) {
        dtr_ = dmp_ = lam_ = mu_ = l2m_ = 0.0f;
        if (i >= 0 && i < kNZP && j >= 0 && j < kNXP) {
            int iz = i - kNPML; iz = iz < 0 ? 0 : (iz > kNZ - 1 ? kNZ - 1 : iz);
            int jx = j - kNPML; jx = jx < 0 ? 0 : (jx > kNX - 1 ? kNX - 1 : jx);
            const float vp  = Vp[iz * kNX + jx];
            const float vs  = Vs[iz * kNX + jx];
            const float rho = Den[iz * kNX + jx];
            const float m = vs * vs * rho * 1e-6f;
            const float l = (vp * vp - 2.0f * vs * vs) * rho * 1e-6f;
            const float sc = kDT * kINV_DX;
            float dz = fmaxf((float)(kNPML - i), (float)(i - (kNZP - 1 - kNPML)));
            dz = fminf(fmaxf(dz, 0.0f), (float)kNPML) * (1.0f / kNPML);
            float dxx = fmaxf((float)(kNPML - j), (float)(j - (kNXP - 1 - kNPML)));
            dxx = fminf(fmaxf(dxx, 0.0f), (float)kNPML) * (1.0f / kNPML);
            dmp_ = expf(-0.1f * (dz * dz + dxx * dxx));
            dtr_ = kDT / rho * kINV_DX;
            lam_ = l * sc;
            mu_  = m * sc;
            l2m_ = (l + 2.0f * m) * sc;
        }
    };
    float rdtr[kR], rdamp[kR], rlam[kR], rmu[kR], rl2m[kR];
    float dtrT = 0, dmpT = 0, dtrB = 0, dmpB = 0;
    if (active) {
#pragma unroll
        for (int r = 0; r < kR; ++r)
            modAt(r0 + r, tid, rdtr[r], rdamp[r], rlam[r], rmu[r], rl2m[r]);
        float d0, d1, d2;
        modAt(r0 - 1, tid, dtrT, dmpT, d0, d1, d2);
        modAt(r0 + kR, tid, dtrB, dmpB, d0, d1, d2);
    }

    const int id  = Shot_ids[s];
    const int sxp = kNPML + 20 + id * ((kNX - 40) / kNSHOTS);
    const float* stf = Stf + id * kNSTEPS;
    const int rsrc = kSRC_Z - r0;
    const int rrec = kREC_Z - r0;
    const float srcm = (active && tid == sxp) ? 1.0f : 0.0f;
    const float recm = (active && (unsigned)(tid - kNPML) < (unsigned)kNX) ? 1.0f : 0.0f;

    const bool hasTop = (slab > 0);
    const bool hasBot = (slab < kNSLAB - 1);
    int* ftopw = hasTop ? &flags[((s * kNB + (slab - 1)) * 2 + 1) * kFlagStride] : nullptr;
    int* fbotw = hasBot ? &flags[((s * kNB + slab) * 2 + 0) * kFlagStride] : nullptr;
    int* ftopr = hasTop ? &flags[((s * kNB + (slab - 1)) * 2 + 0) * kFlagStride] : nullptr;
    int* fbotr = hasBot ? &flags[((s * kNB + slab) * 2 + 1) * kFlagStride] : nullptr;
    auto hbase = [&](int buf, int b, int dir) {
        return halo + ((((buf * kNSHOTS + s) * kNB + b) * 2 + dir) * 6) * kNXP;
    };

    float fvx[kR]  = {}, fvz[kR]  = {}, fsxx[kR] = {}, fszz[kR] = {}, fsxz[kR] = {};
    float rsum = 0.0f;
    __syncthreads();

    for (int t = 0; t < kNSTEPS; ++t) {
        const int rb = (t & 1) ^ 1;        // read buffer (step t-1 data)
        const int wb = t & 1;              // write buffer (step t data)
        if (t > 0) {
            if (tid == 0 && hasTop) {
                while (__hip_atomic_load(ftopr, __ATOMIC_RELAXED, __HIP_MEMORY_SCOPE_AGENT) < t) {}
            }
            if (tid == 1 && hasBot) {
                while (__hip_atomic_load(fbotr, __ATOMIC_RELAXED, __HIP_MEMORY_SCOPE_AGENT) < t) {}
            }
        }
        __syncthreads();
        if (t > 0) __builtin_amdgcn_fence(__ATOMIC_ACQUIRE, "agent");

        // halo slots — dir0 (from top): vx[R-1],vz[R-1],sxx[R-1],szz[R-1],sxz[R-1],sxz[R-2]
        //              dir1 (from bot): vx[0],vz[0],sxx[0],sxz[0],szz[0],szz[1]
        float h_vxT = 0, h_vzT = 0, h_sxxT = 0, h_szzT = 0, h_sxzT = 0, h_sxz2T = 0;
        float h_sxxT_r = 0, h_sxzT_l = 0;
        float h_vxB = 0, h_vzB = 0, h_sxxB = 0, h_sxzB = 0, h_szzB = 0, h_szz2B = 0;
        float h_sxxB_r = 0, h_sxzB_l = 0;
        if (t > 0 && active && hasTop) {
            const float* hb = hbase(rb, slab - 1, 0);
            h_vxT   = hb[tid];
            h_vzT   = hb[kNXP + tid];
            h_sxxT  = hb[2 * kNXP + tid];
            h_szzT  = hb[3 * kNXP + tid];
            h_sxzT  = hb[4 * kNXP + tid];
            h_sxz2T = hb[5 * kNXP + tid];
            if (tid < kNXP - 1) h_sxxT_r = hb[2 * kNXP + tid + 1];
            if (tid > 0)        h_sxzT_l = hb[4 * kNXP + tid - 1];
        }
        if (t > 0 && active && hasBot) {
            const float* hb = hbase(rb, slab, 1);
            h_vxB   = hb[tid];
            h_vzB   = hb[kNXP + tid];
            h_sxxB  = hb[2 * kNXP + tid];
            h_sxzB  = hb[3 * kNXP + tid];
            h_szzB  = hb[4 * kNXP + tid];
            h_szz2B = hb[5 * kNXP + tid];
            if (tid < kNXP - 1) h_sxxB_r = hb[2 * kNXP + tid + 1];
            if (tid > 0)        h_sxzB_l = hb[3 * kNXP + tid - 1];
        }

        // ---- velocity(t): redundant rows -1 and kR, plus own rows 0..kR-1 ----
        float nvxT = 0, nvzT = 0, nvxB = 0, nvzB = 0;
        if (active) {
            nvxT = (h_vxT + dtrT * ((h_sxxT_r - h_sxxT) + (h_sxzT - h_sxz2T))) * dmpT;
            nvzT = (h_vzT + dtrT * ((h_sxzT - h_sxzT_l) + (fszz[0] - h_szzT))) * dmpT;
            nvxB = (h_vxB + dtrB * ((h_sxxB_r - h_sxxB) + (h_sxzB - fsxz[kR - 1]))) * dmpB;
            nvzB = (h_vzB + dtrB * ((h_sxzB - h_sxzB_l) + (h_szz2B - h_szzB))) * dmpB;
#pragma unroll
            for (int r = 0; r < kR; ++r) {
                const float sxxC = fsxx[r];
                const float sxzC = fsxz[r];
                const float szzC = fszz[r];
                const float sxxR = Lsxx[r * kPitch + lc + 1];
                const float sxzL = Lsxz[r * kPitch + lc - 1];
                const float sxzU = (r > 0) ? fsxz[r - 1] : h_sxzT;
                const float szzD = (r < kR - 1) ? fszz[r + 1] : h_szzB;
                const float nvx = (fvx[r] + rdtr[r] * ((sxxR - sxxC) + (sxzC - sxzU))) * rdamp[r];
                const float nvz = (fvz[r] + rdtr[r] * ((sxzC - sxzL) + (szzD - szzC))) * rdamp[r];
                fvx[r] = nvx;
                fvz[r] = nvz;
                Lvx[r * kPitch + lc] = nvx;
                Lvz[r * kPitch + lc] = nvz;
                if (r == rrec) rsum += recm * nvx * nvx;
            }
        }
        __syncthreads();

        // ---- stress(t): own rows 0..kR-1; source; publish halos (plain) ----
        if (active) {
            const float sval = stf[t] * kDT;
#pragma unroll
            for (int r = 0; r < kR; ++r) {
                const float vxC = fvx[r];
                const float vzC = fvz[r];
                const float vxL = Lvx[r * kPitch + lc - 1];
                const float vzR = Lvz[r * kPitch + lc + 1];
                const float vzU = (r > 0) ? fvz[r - 1] : nvzT;
                const float vxD = (r < kR - 1) ? fvx[r + 1] : nvxB;
                const float dvx = vxC - vxL;
                const float dvz = vzC - vzU;
                float nsxx = (fsxx[r] + (rl2m[r] * dvx + rlam[r] * dvz)) * rdamp[r];
                float nszz = (fszz[r] + (rlam[r] * dvx + rl2m[r] * dvz)) * rdamp[r];
                float nsxz = (fsxz[r] + rmu[r] * ((vxD - vxC) + (vzR - vzC))) * rdamp[r];
                if (r == rsrc) { nsxx += srcm * sval; nszz += srcm * sval; }
                fsxx[r] = nsxx;
                fszz[r] = nszz;
                fsxz[r] = nsxz;
                Lsxx[r * kPitch + lc] = nsxx;
                Lsxz[r * kPitch + lc] = nsxz;
            }
            if (hasTop) {   // up (dir1): vx0,vz0,sxx0,sxz0,szz0,szz1
                float* hb = hbase(wb, slab - 1, 1);
                hb[tid]            = fvx[0];
                hb[kNXP + tid]     = fvz[0];
                hb[2 * kNXP + tid] = fsxx[0];
                hb[3 * kNXP + tid] = fsxz[0];
                hb[4 * kNXP + tid] = fszz[0];
                hb[5 * kNXP + tid] = fszz[1];
            }
            if (hasBot) {   // down (dir0): vx[R-1],vz[R-1],sxx[R-1],szz[R-1],sxz[R-1],sxz[R-2]
                float* hb = hbase(wb, slab, 0);
                hb[tid]            = fvx[kR - 1];
                hb[kNXP + tid]     = fvz[kR - 1];
                hb[2 * kNXP + tid] = fsxx[kR - 1];
                hb[3 * kNXP + tid] = fszz[kR - 1];
                hb[4 * kNXP + tid] = fsxz[kR - 1];
                hb[5 * kNXP + tid] = fsxz[kR - 2];
            }
        }
        __syncthreads();   // drains all halo stores to L2 (vmcnt) for all waves
        if (tid < 2) {
            // release: write back L2 to the agent coherence point, then flag
            __builtin_amdgcn_fence(__ATOMIC_RELEASE, "agent");
            if (tid == 0 && hasTop) __hip_atomic_store(ftopw, t + 1, __ATOMIC_RELAXED, __HIP_MEMORY_SCOPE_AGENT);
            if (tid == 1 && hasBot) __hip_atomic_store(fbotw, t + 1, __ATOMIC_RELAXED, __HIP_MEMORY_SCOPE_AGENT);
        }
    }

    for (int off = 32; off > 0; off >>= 1) rsum += __shfl_down(rsum, off, 64);
    if ((tid & 63) == 0 && rsum != 0.0f) atomicAdd(lossp, rsum);
}

__global__ void fwi_finish_kernel(const float* __restrict__ ws,
                                  float* __restrict__ out) {
    out[0] = 0.5f * ws[kLossOff];
}

extern "C" void kernel_launch(void* const* d_in, const int* in_sizes, int n_in,
                              void* d_out, int out_size, void* d_ws, size_t ws_size,
                              hipStream_t stream) {
    const float* Vp  = (const float*)d_in[0];
    const float* Vs  = (const float*)d_in[1];
    const float* Den = (const float*)d_in[2];
    const float* Stf = (const float*)d_in[3];
    // d_in[4] = Mask (all-ones; identity in forward value) -- unused
    const int* Shot_ids = (const int*)d_in[5];
    float* out = (float*)d_out;
    float* ws  = (float*)d_ws;

    fwi_init_ws<<<16, 256, 0, stream>>>(ws);
    void* args[] = {(void*)&Vp, (void*)&Vs, (void*)&Den, (void*)&Stf,
                    (void*)&Shot_ids, (void*)&ws};
    hipLaunchCooperativeKernel((const void*)fwi_sim_kernel, dim3(kBlocks),
                               dim3(kThreads), args, 0, stream);
    fwi_finish_kernel<<<1, 1, 0, stream>>>(ws, out);
}

// Round 14
// 637.757 us; speedup vs baseline: 5.9109x; 5.9109x over previous
//
#include <hip/hip_runtime.h>
#include <cmath>

namespace {
constexpr int kNZ = 300, kNX = 400;
constexpr int kNPML = 32;
constexpr int kNZP = 364, kNXP = 464;        // padded physical grid
constexpr int kNSTEPS = 200, kNSHOTS = 2;
constexpr int kSRC_Z = 34, kREC_Z = 34;      // NPML + 2
constexpr float kDT = 0.001f;
constexpr float kINV_DX = 100.0f;            // 1/DX

// persistent slab decomposition — kR=4 (r11-verified geometry/numerics)
constexpr int kR = 4;                         // rows per slab
constexpr int kNSLAB = 92;                    // 368 rows; 364..367 dead (zero moduli)
constexpr int kNB = kNSLAB - 1;               // 91 boundaries
constexpr int kBlocks = kNSHOTS * kNSLAB;     // 184 blocks, all co-resident
constexpr int kThreads = 512;                 // one column per thread (464 active)
constexpr int kPitch = 468;                   // LDS row pitch (guard cols 0,465)
constexpr int kFStride = kR * kPitch;         // 1872

// ws layout (floats / ints):
//   [0, 16384)   : int flags[shot][b][dir] padded x32 (128B line isolation)
//   [16384, ...) : float halo[buf][shot][b][dir][slot(6)][464]  (double-buffered)
//   loss         : 1 float after halos
constexpr int kFlagStride = 32;
constexpr int kHaloBase = 16384;
constexpr int kHaloCount = 2 * kNSHOTS * kNB * 2 * 6 * kNXP;   // 2,026,752
constexpr int kLossOff = kHaloBase + kHaloCount;
}  // namespace

__global__ void fwi_init_ws(float* __restrict__ ws) {
    const int gtid = blockIdx.x * blockDim.x + threadIdx.x;
    const int gstride = gridDim.x * blockDim.x;
    for (int q = gtid; q <= kLossOff; q += gstride) ws[q] = 0.0f;
}

// Persistent kernel, ONE neighbor sync per timestep. r11 protocol (per-element
// agent-scope atomics for halo data + relaxed monotonic flags — fastest of the
// three protocols measured in r10/r11/r13). NEW (r14): interior velocity rows
// 1..kR-2 are computed BEFORE the flag wait (they need no halo), overlapping
// the neighbor-publish RTT; only boundary rows 0/kR-1 + ghost rows sit on the
// post-detect critical path. Flags padded to 128B lines.
__global__ __launch_bounds__(kThreads, 1) void fwi_sim_kernel(
    const float* __restrict__ Vp, const float* __restrict__ Vs,
    const float* __restrict__ Den, const float* __restrict__ Stf,
    const int* __restrict__ Shot_ids, float* __restrict__ ws) {
    __shared__ float L[4 * kFStride];   // 29952 B
    float* Lvx  = L;
    float* Lvz  = L + kFStride;
    float* Lsxx = L + 2 * kFStride;
    float* Lsxz = L + 3 * kFStride;

    const int blk  = blockIdx.x;
    const int s    = blk / kNSLAB;
    const int slab = blk - s * kNSLAB;
    const int r0   = slab * kR;
    const int tid  = threadIdx.x;
    const bool active = tid < kNXP;
    const int lc = tid + 1;

    int*   flags = (int*)ws;
    float* halo  = ws + kHaloBase;
    float* lossp = ws + kLossOff;

    for (int q = tid; q < 4 * kFStride; q += kThreads) L[q] = 0.0f;

    auto modAt = [&](int i, int j, float& dtr_, float& dmp_, float& lam_,
                     float& mu_, float& l2m_) {
        dtr_ = dmp_ = lam_ = mu_ = l2m_ = 0.0f;
        if (i >= 0 && i < kNZP && j >= 0 && j < kNXP) {
            int iz = i - kNPML; iz = iz < 0 ? 0 : (iz > kNZ - 1 ? kNZ - 1 : iz);
            int jx = j - kNPML; jx = jx < 0 ? 0 : (jx > kNX - 1 ? kNX - 1 : jx);
            const float vp  = Vp[iz * kNX + jx];
            const float vs  = Vs[iz * kNX + jx];
            const float rho = Den[iz * kNX + jx];
            const float m = vs * vs * rho * 1e-6f;
            const float l = (vp * vp - 2.0f * vs * vs) * rho * 1e-6f;
            const float sc = kDT * kINV_DX;
            float dz = fmaxf((float)(kNPML - i), (float)(i - (kNZP - 1 - kNPML)));
            dz = fminf(fmaxf(dz, 0.0f), (float)kNPML) * (1.0f / kNPML);
            float dxx = fmaxf((float)(kNPML - j), (float)(j - (kNXP - 1 - kNPML)));
            dxx = fminf(fmaxf(dxx, 0.0f), (float)kNPML) * (1.0f / kNPML);
            dmp_ = expf(-0.1f * (dz * dz + dxx * dxx));
            dtr_ = kDT / rho * kINV_DX;
            lam_ = l * sc;
            mu_  = m * sc;
            l2m_ = (l + 2.0f * m) * sc;
        }
    };
    float rdtr[kR], rdamp[kR], rlam[kR], rmu[kR], rl2m[kR];
    float dtrT = 0, dmpT = 0, dtrB = 0, dmpB = 0;
    if (active) {
#pragma unroll
        for (int r = 0; r < kR; ++r)
            modAt(r0 + r, tid, rdtr[r], rdamp[r], rlam[r], rmu[r], rl2m[r]);
        float d0, d1, d2;
        modAt(r0 - 1, tid, dtrT, dmpT, d0, d1, d2);
        modAt(r0 + kR, tid, dtrB, dmpB, d0, d1, d2);
    }

    const int id  = Shot_ids[s];
    const int sxp = kNPML + 20 + id * ((kNX - 40) / kNSHOTS);
    const float* stf = Stf + id * kNSTEPS;
    const int rsrc = kSRC_Z - r0;
    const int rrec = kREC_Z - r0;
    const float srcm = (active && tid == sxp) ? 1.0f : 0.0f;
    const float recm = (active && (unsigned)(tid - kNPML) < (unsigned)kNX) ? 1.0f : 0.0f;

    const bool hasTop = (slab > 0);
    const bool hasBot = (slab < kNSLAB - 1);
    int* ftopw = hasTop ? &flags[((s * kNB + (slab - 1)) * 2 + 1) * kFlagStride] : nullptr;
    int* fbotw = hasBot ? &flags[((s * kNB + slab) * 2 + 0) * kFlagStride] : nullptr;
    int* ftopr = hasTop ? &flags[((s * kNB + (slab - 1)) * 2 + 0) * kFlagStride] : nullptr;
    int* fbotr = hasBot ? &flags[((s * kNB + slab) * 2 + 1) * kFlagStride] : nullptr;
    auto hbase = [&](int buf, int b, int dir) {
        return halo + ((((buf * kNSHOTS + s) * kNB + b) * 2 + dir) * 6) * kNXP;
    };

    float fvx[kR]  = {}, fvz[kR]  = {}, fsxx[kR] = {}, fszz[kR] = {}, fsxz[kR] = {};
    float rsum = 0.0f;
    __syncthreads();

    for (int t = 0; t < kNSTEPS; ++t) {
        const int rb = (t & 1) ^ 1;        // read buffer (step t-1 data)
        const int wb = t & 1;              // write buffer (step t data)

        // ---- pre-wait: interior velocity rows 1..kR-2 (no halo needed);
        //      overlaps the neighbor-publish RTT. Uses t-1 stress (regs+LDS,
        //      ordered by previous iteration's final barrier).
        if (active) {
#pragma unroll
            for (int r = 1; r <= kR - 2; ++r) {
                const float sxxC = fsxx[r];
                const float sxzC = fsxz[r];
                const float szzC = fszz[r];
                const float sxxR = Lsxx[r * kPitch + lc + 1];
                const float sxzL = Lsxz[r * kPitch + lc - 1];
                const float nvx = (fvx[r] + rdtr[r] * ((sxxR - sxxC) + (sxzC - fsxz[r - 1]))) * rdamp[r];
                const float nvz = (fvz[r] + rdtr[r] * ((sxzC - sxzL) + (fszz[r + 1] - szzC))) * rdamp[r];
                fvx[r] = nvx;
                fvz[r] = nvz;
                Lvx[r * kPitch + lc] = nvx;
                Lvz[r * kPitch + lc] = nvz;
                if (r == rrec) rsum += recm * nvx * nvx;
            }
        }

        // ---- wait for neighbors' step t-1 data ----
        if (tid == 0 && hasTop) {
            while (__hip_atomic_load(ftopr, __ATOMIC_RELAXED, __HIP_MEMORY_SCOPE_AGENT) < t) {}
        }
        if (tid == 1 && hasBot) {
            while (__hip_atomic_load(fbotr, __ATOMIC_RELAXED, __HIP_MEMORY_SCOPE_AGENT) < t) {}
        }
        __syncthreads();

        // halo slots — dir0 (from top): vx[R-1],vz[R-1],sxx[R-1],szz[R-1],sxz[R-1],sxz[R-2]
        //              dir1 (from bot): vx[0],vz[0],sxx[0],sxz[0],szz[0],szz[1]
        float h_vxT = 0, h_vzT = 0, h_sxxT = 0, h_szzT = 0, h_sxzT = 0, h_sxz2T = 0;
        float h_sxxT_r = 0, h_sxzT_l = 0;
        float h_vxB = 0, h_vzB = 0, h_sxxB = 0, h_sxzB = 0, h_szzB = 0, h_szz2B = 0;
        float h_sxxB_r = 0, h_sxzB_l = 0;
        if (active && hasTop) {
            const float* hb = hbase(rb, slab - 1, 0);
            h_vxT   = __hip_atomic_load(hb + tid,             __ATOMIC_RELAXED, __HIP_MEMORY_SCOPE_AGENT);
            h_vzT   = __hip_atomic_load(hb + kNXP + tid,      __ATOMIC_RELAXED, __HIP_MEMORY_SCOPE_AGENT);
            h_sxxT  = __hip_atomic_load(hb + 2 * kNXP + tid,  __ATOMIC_RELAXED, __HIP_MEMORY_SCOPE_AGENT);
            h_szzT  = __hip_atomic_load(hb + 3 * kNXP + tid,  __ATOMIC_RELAXED, __HIP_MEMORY_SCOPE_AGENT);
            h_sxzT  = __hip_atomic_load(hb + 4 * kNXP + tid,  __ATOMIC_RELAXED, __HIP_MEMORY_SCOPE_AGENT);
            h_sxz2T = __hip_atomic_load(hb + 5 * kNXP + tid,  __ATOMIC_RELAXED, __HIP_MEMORY_SCOPE_AGENT);
            if (tid < kNXP - 1) h_sxxT_r = __hip_atomic_load(hb + 2 * kNXP + tid + 1, __ATOMIC_RELAXED, __HIP_MEMORY_SCOPE_AGENT);
            if (tid > 0)        h_sxzT_l = __hip_atomic_load(hb + 4 * kNXP + tid - 1, __ATOMIC_RELAXED, __HIP_MEMORY_SCOPE_AGENT);
        }
        if (active && hasBot) {
            const float* hb = hbase(rb, slab, 1);
            h_vxB   = __hip_atomic_load(hb + tid,             __ATOMIC_RELAXED, __HIP_MEMORY_SCOPE_AGENT);
            h_vzB   = __hip_atomic_load(hb + kNXP + tid,      __ATOMIC_RELAXED, __HIP_MEMORY_SCOPE_AGENT);
            h_sxxB  = __hip_atomic_load(hb + 2 * kNXP + tid,  __ATOMIC_RELAXED, __HIP_MEMORY_SCOPE_AGENT);
            h_sxzB  = __hip_atomic_load(hb + 3 * kNXP + tid,  __ATOMIC_RELAXED, __HIP_MEMORY_SCOPE_AGENT);
            h_szzB  = __hip_atomic_load(hb + 4 * kNXP + tid,  __ATOMIC_RELAXED, __HIP_MEMORY_SCOPE_AGENT);
            h_szz2B = __hip_atomic_load(hb + 5 * kNXP + tid,  __ATOMIC_RELAXED, __HIP_MEMORY_SCOPE_AGENT);
            if (tid < kNXP - 1) h_sxxB_r = __hip_atomic_load(hb + 2 * kNXP + tid + 1, __ATOMIC_RELAXED, __HIP_MEMORY_SCOPE_AGENT);
            if (tid > 0)        h_sxzB_l = __hip_atomic_load(hb + 3 * kNXP + tid - 1, __ATOMIC_RELAXED, __HIP_MEMORY_SCOPE_AGENT);
        }

        // ---- boundary velocity: ghost rows -1,kR + own rows 0,kR-1 ----
        // (fszz[1], fsxz[kR-2] are still t-1 values: stress phase not yet run)
        float nvxT = 0, nvzT = 0, nvxB = 0, nvzB = 0;
        if (active) {
            nvxT = (h_vxT + dtrT * ((h_sxxT_r - h_sxxT) + (h_sxzT - h_sxz2T))) * dmpT;
            nvzT = (h_vzT + dtrT * ((h_sxzT - h_sxzT_l) + (fszz[0] - h_szzT))) * dmpT;
            nvxB = (h_vxB + dtrB * ((h_sxxB_r - h_sxxB) + (h_sxzB - fsxz[kR - 1]))) * dmpB;
            nvzB = (h_vzB + dtrB * ((h_sxzB - h_sxzB_l) + (h_szz2B - h_szzB))) * dmpB;
            {   // row 0
                const float sxxC = fsxx[0], sxzC = fsxz[0], szzC = fszz[0];
                const float sxxR = Lsxx[lc + 1];
                const float sxzL = Lsxz[lc - 1];
                const float nvx = (fvx[0] + rdtr[0] * ((sxxR - sxxC) + (sxzC - h_sxzT))) * rdamp[0];
                const float nvz = (fvz[0] + rdtr[0] * ((sxzC - sxzL) + (fszz[1] - szzC))) * rdamp[0];
                fvx[0] = nvx; fvz[0] = nvz;
                Lvx[lc] = nvx; Lvz[lc] = nvz;
                if (0 == rrec) rsum += recm * nvx * nvx;
            }
            {   // row kR-1
                const int r = kR - 1;
                const float sxxC = fsxx[r], sxzC = fsxz[r], szzC = fszz[r];
                const float sxxR = Lsxx[r * kPitch + lc + 1];
                const float sxzL = Lsxz[r * kPitch + lc - 1];
                const float nvx = (fvx[r] + rdtr[r] * ((sxxR - sxxC) + (sxzC - fsxz[r - 1]))) * rdamp[r];
                const float nvz = (fvz[r] + rdtr[r] * ((sxzC - sxzL) + (h_szzB - szzC))) * rdamp[r];
                fvx[r] = nvx; fvz[r] = nvz;
                Lvx[r * kPitch + lc] = nvx; Lvz[r * kPitch + lc] = nvz;
                if (r == rrec) rsum += recm * nvx * nvx;
            }
        }
        __syncthreads();

        // ---- stress(t): rows 0..kR-1; source; publish halos ----
        if (active) {
            const float sval = stf[t] * kDT;
#pragma unroll
            for (int r = 0; r < kR; ++r) {
                const float vxC = fvx[r];
                const float vzC = fvz[r];
                const float vxL = Lvx[r * kPitch + lc - 1];
                const float vzR = Lvz[r * kPitch + lc + 1];
                const float vzU = (r > 0) ? fvz[r - 1] : nvzT;
                const float vxD = (r < kR - 1) ? fvx[r + 1] : nvxB;
                const float dvx = vxC - vxL;
                const float dvz = vzC - vzU;
                float nsxx = (fsxx[r] + (rl2m[r] * dvx + rlam[r] * dvz)) * rdamp[r];
                float nszz = (fszz[r] + (rlam[r] * dvx + rl2m[r] * dvz)) * rdamp[r];
                float nsxz = (fsxz[r] + rmu[r] * ((vxD - vxC) + (vzR - vzC))) * rdamp[r];
                if (r == rsrc) { nsxx += srcm * sval; nszz += srcm * sval; }
                fsxx[r] = nsxx;
                fszz[r] = nszz;
                fsxz[r] = nsxz;
                Lsxx[r * kPitch + lc] = nsxx;
                Lsxz[r * kPitch + lc] = nsxz;
            }
            if (hasTop) {   // up (dir1): vx0,vz0,sxx0,sxz0,szz0,szz1
                float* hb = hbase(wb, slab - 1, 1);
                __hip_atomic_store(hb + tid,            fvx[0],  __ATOMIC_RELAXED, __HIP_MEMORY_SCOPE_AGENT);
                __hip_atomic_store(hb + kNXP + tid,     fvz[0],  __ATOMIC_RELAXED, __HIP_MEMORY_SCOPE_AGENT);
                __hip_atomic_store(hb + 2 * kNXP + tid, fsxx[0], __ATOMIC_RELAXED, __HIP_MEMORY_SCOPE_AGENT);
                __hip_atomic_store(hb + 3 * kNXP + tid, fsxz[0], __ATOMIC_RELAXED, __HIP_MEMORY_SCOPE_AGENT);
                __hip_atomic_store(hb + 4 * kNXP + tid, fszz[0], __ATOMIC_RELAXED, __HIP_MEMORY_SCOPE_AGENT);
                __hip_atomic_store(hb + 5 * kNXP + tid, fszz[1], __ATOMIC_RELAXED, __HIP_MEMORY_SCOPE_AGENT);
            }
            if (hasBot) {   // down (dir0): vx[R-1],vz[R-1],sxx[R-1],szz[R-1],sxz[R-1],sxz[R-2]
                float* hb = hbase(wb, slab, 0);
                __hip_atomic_store(hb + tid,            fvx[kR - 1],  __ATOMIC_RELAXED, __HIP_MEMORY_SCOPE_AGENT);
                __hip_atomic_store(hb + kNXP + tid,     fvz[kR - 1],  __ATOMIC_RELAXED, __HIP_MEMORY_SCOPE_AGENT);
                __hip_atomic_store(hb + 2 * kNXP + tid, fsxx[kR - 1], __ATOMIC_RELAXED, __HIP_MEMORY_SCOPE_AGENT);
                __hip_atomic_store(hb + 3 * kNXP + tid, fszz[kR - 1], __ATOMIC_RELAXED, __HIP_MEMORY_SCOPE_AGENT);
                __hip_atomic_store(hb + 4 * kNXP + tid, fsxz[kR - 1], __ATOMIC_RELAXED, __HIP_MEMORY_SCOPE_AGENT);
                __hip_atomic_store(hb + 5 * kNXP + tid, fsxz[kR - 2], __ATOMIC_RELAXED, __HIP_MEMORY_SCOPE_AGENT);
            }
        }
        __syncthreads();   // drains halo stores (vmcnt) before flag publish
        if (tid == 0 && hasTop) __hip_atomic_store(ftopw, t + 1, __ATOMIC_RELAXED, __HIP_MEMORY_SCOPE_AGENT);
        if (tid == 1 && hasBot) __hip_atomic_store(fbotw, t + 1, __ATOMIC_RELAXED, __HIP_MEMORY_SCOPE_AGENT);
    }

    for (int off = 32; off > 0; off >>= 1) rsum += __shfl_down(rsum, off, 64);
    if ((tid & 63) == 0 && rsum != 0.0f) atomicAdd(lossp, rsum);
}

__global__ void fwi_finish_kernel(const float* __restrict__ ws,
                                  float* __restrict__ out) {
    out[0] = 0.5f * ws[kLossOff];
}

extern "C" void kernel_launch(void* const* d_in, const int* in_sizes, int n_in,
                              void* d_out, int out_size, void* d_ws, size_t ws_size,
                              hipStream_t stream) {
    const float* Vp  = (const float*)d_in[0];
    const float* Vs  = (const float*)d_in[1];
    const float* Den = (const float*)d_in[2];
    const float* Stf = (const float*)d_in[3];
    // d_in[4] = Mask (all-ones; identity in forward value) -- unused
    const int* Shot_ids = (const int*)d_in[5];
    float* out = (float*)d_out;
    float* ws  = (float*)d_ws;

    fwi_init_ws<<<256, 256, 0, stream>>>(ws);
    void* args[] = {(void*)&Vp, (void*)&Vs, (void*)&Den, (void*)&Stf,
                    (void*)&Shot_ids, (void*)&ws};
    hipLaunchCooperativeKernel((const void*)fwi_sim_kernel, dim3(kBlocks),
                               dim3(kThreads), args, 0, stream);
    fwi_finish_kernel<<<1, 1, 0, stream>>>(ws, out);
}